// Round 4
// baseline (294.992 us; speedup 1.0000x reference)
//
#include <hip/hip_runtime.h>
#include <hip/hip_cooperative_groups.h>

namespace cg = cooperative_groups;

#define NBINS 256
#define SLOT (6 * NBINS)   // ints per partial-histogram slot
#define FNB  256           // fused grid: 256 blocks (1/CU, co-resident)
#define FTH  1024          // fused block size

// cs[i] = clip(-1 + i/127, -1, 1) computed exactly as the reference (fp32 ops)
__device__ __forceinline__ float csv(int i) {
    float c = -1.0f + (float)i / 127.0f;
    return fminf(fmaxf(c, -1.0f), 1.0f);
}

__device__ __forceinline__ int binof(float v) {
    v = fminf(fmaxf(v, -1.0f), 1.0f);
    int b = (int)((v + 1.0f) * 128.0f);   // trunc toward zero == astype(int32)
    return min(max(b, 0), NBINS - 1);
}

__device__ __forceinline__ float map_one(float x, const float* __restrict__ y,
                                         const float* __restrict__ cs) {
    if (x <= -1.0f) return y[0];
    if (x >= 1.0f)  return y[NBINS - 1];
    float kf = (x + 1.0f) * 127.0f;
    int k = (int)(kf + 0.5f);
    int lo = max(k - 1, 0);
    int hi = min(k + 1, NBINS - 1);
    int ind1 = lo;
    float best = fabsf(cs[lo] - x);
    for (int j = lo + 1; j <= hi; j++) {
        float d = fabsf(cs[j] - x);
        if (d < best) { best = d; ind1 = j; }   // strict < => first-min
    }
    int ind0 = max(ind1 - 1, 0);
    float x0 = cs[ind0], x1 = cs[ind1];
    float y0 = y[ind0],  y1 = y[ind1];
    float denom = x1 - x0;
    float safe = (denom == 0.0f) ? 1.0f : denom;
    return y0 + (y1 - y0) * (x - x0) / safe;
}

// ---------------------------------------------------------------------------
// FUSED cooperative kernel: 256 blocks x 1024 threads (1 block/CU).
// Phase A: per-block private hist (LDS atomics) -> partials[block][6][256]
// Phase B: blocks 0..2 reduce 256 slots (4-way ILP groups), scan, pxmap
// Phase C: all blocks map src -> out (src is L2-hot from phase A)
// Two grid.sync()s replace three dispatch boundaries.
// ---------------------------------------------------------------------------
__global__ __launch_bounds__(FTH) void hm_fused(const float* __restrict__ src,
                                                const float* __restrict__ tgt,
                                                float* __restrict__ out,
                                                int ngroups, int n,
                                                float pixcnt_m1,
                                                float* __restrict__ pxmap,
                                                int* __restrict__ partials) {
    cg::grid_group grid = cg::this_grid();

    __shared__ int lh[8 * NBINS];          // phase A uses [0,6*256); B uses all 8 rows
    __shared__ int ss[NBINS], st[NBINS];
    __shared__ float cdfs[NBINS], cdft[NBINS];
    __shared__ float pm[3 * NBINS];
    __shared__ float cstab[NBINS];

    const int t = threadIdx.x;

    // ---------------- Phase A: histogram ----------------
    for (int i = t; i < SLOT; i += FTH) lh[i] = 0;
    __syncthreads();

    const float4* __restrict__ s4 = (const float4*)src;
    const float4* __restrict__ t4 = (const float4*)tgt;
    const int stride = gridDim.x * blockDim.x;
    for (int g = blockIdx.x * blockDim.x + t; g < ngroups; g += stride) {
        int b = g * 3;   // float4 index; covers flat elements 12g .. 12g+11
        float4 s0 = s4[b], s1 = s4[b + 1], s2 = s4[b + 2];
        float4 t0 = t4[b], t1 = t4[b + 1], t2 = t4[b + 2];
        atomicAdd(&lh[0 * NBINS + binof(s0.x)], 1);
        atomicAdd(&lh[1 * NBINS + binof(s0.y)], 1);
        atomicAdd(&lh[2 * NBINS + binof(s0.z)], 1);
        atomicAdd(&lh[0 * NBINS + binof(s0.w)], 1);
        atomicAdd(&lh[1 * NBINS + binof(s1.x)], 1);
        atomicAdd(&lh[2 * NBINS + binof(s1.y)], 1);
        atomicAdd(&lh[0 * NBINS + binof(s1.z)], 1);
        atomicAdd(&lh[1 * NBINS + binof(s1.w)], 1);
        atomicAdd(&lh[2 * NBINS + binof(s2.x)], 1);
        atomicAdd(&lh[0 * NBINS + binof(s2.y)], 1);
        atomicAdd(&lh[1 * NBINS + binof(s2.z)], 1);
        atomicAdd(&lh[2 * NBINS + binof(s2.w)], 1);

        atomicAdd(&lh[3 * NBINS + binof(t0.x)], 1);
        atomicAdd(&lh[4 * NBINS + binof(t0.y)], 1);
        atomicAdd(&lh[5 * NBINS + binof(t0.z)], 1);
        atomicAdd(&lh[3 * NBINS + binof(t0.w)], 1);
        atomicAdd(&lh[4 * NBINS + binof(t1.x)], 1);
        atomicAdd(&lh[5 * NBINS + binof(t1.y)], 1);
        atomicAdd(&lh[3 * NBINS + binof(t1.z)], 1);
        atomicAdd(&lh[4 * NBINS + binof(t1.w)], 1);
        atomicAdd(&lh[5 * NBINS + binof(t2.x)], 1);
        atomicAdd(&lh[3 * NBINS + binof(t2.y)], 1);
        atomicAdd(&lh[4 * NBINS + binof(t2.z)], 1);
        atomicAdd(&lh[5 * NBINS + binof(t2.w)], 1);
    }
    // scalar tail (n not divisible by 12)
    if (blockIdx.x == 0) {
        int base = ngroups * 12;
        int rem = n - base;
        if (t < rem) {
            int j = base + t;
            int c = j % 3;
            atomicAdd(&lh[c * NBINS + binof(src[j])], 1);
            atomicAdd(&lh[(3 + c) * NBINS + binof(tgt[j])], 1);
        }
    }
    __syncthreads();

    {
        int* dst = partials + blockIdx.x * SLOT;
        for (int i = t; i < SLOT; i += FTH) dst[i] = lh[i];
    }

    __threadfence();
    grid.sync();

    // ---------------- Phase B: tables (blocks 0..2) ----------------
    if (blockIdx.x < 3) {
        const int c = blockIdx.x;
        const int grp = t >> 8;     // 0..3
        const int bin = t & 255;

        int as = 0, at = 0;
        const int offS = c * NBINS + bin;
        const int offT = (3 + c) * NBINS + bin;
        #pragma unroll 8
        for (int b = grp; b < FNB; b += 4) {   // 64 iterations, independent loads
            const int* p = partials + b * SLOT;
            as += p[offS];
            at += p[offT];
        }
        lh[grp * NBINS + bin] = as;            // rows 0..3: src partial sums
        lh[(4 + grp) * NBINS + bin] = at;      // rows 4..7: tgt partial sums
        __syncthreads();

        if (t < NBINS) {
            ss[t] = lh[0 * NBINS + t] + lh[1 * NBINS + t] + lh[2 * NBINS + t] + lh[3 * NBINS + t];
        } else if (t < 2 * NBINS) {
            int b = t - NBINS;
            st[b] = lh[4 * NBINS + b] + lh[5 * NBINS + b] + lh[6 * NBINS + b] + lh[7 * NBINS + b];
        }
        __syncthreads();

        // Hillis-Steele inclusive scan; threads [0,256) scan ss, [256,512) scan st
        for (int off = 1; off < NBINS; off <<= 1) {
            int a = 0; bool act = false;
            if (t < NBINS) {
                if (t >= off) { a = ss[t - off]; act = true; }
            } else if (t < 2 * NBINS) {
                int b = t - NBINS;
                if (b >= off) { a = st[b - off]; act = true; }
            }
            __syncthreads();
            if (act) {
                if (t < NBINS) ss[t] += a;
                else st[t - NBINS] += a;
            }
            __syncthreads();
        }

        if (t < NBINS) {
            int mins = ss[0];                  // cdf nondecreasing -> min = cdf[0]
            cdfs[t] = (float)(ss[t] - mins) * 2.0f / pixcnt_m1 - 1.0f;
        } else if (t < 2 * NBINS) {
            int b = t - NBINS;
            int mint = st[0];
            cdft[b] = (float)(st[b] - mint) * 2.0f / pixcnt_m1 - 1.0f;
        }
        __syncthreads();

        if (t < NBINS) {
            // pxmap[t] = _interpolate(dx=cdftgt, dy=cs, x=cdfsrc[t]); first-min argmin
            float x = cdfs[t];
            int ind1 = 0;
            float best = fabsf(cdft[0] - x);
            for (int i = 1; i < NBINS; i++) {
                float d = fabsf(cdft[i] - x);
                if (d < best) { best = d; ind1 = i; }
            }
            int ind0 = max(ind1 - 1, 0);
            float x0 = cdft[ind0], x1 = cdft[ind1];
            float y0 = csv(ind0),  y1 = csv(ind1);
            float denom = x1 - x0;
            float safe = (denom == 0.0f) ? 1.0f : denom;
            float interp = y0 + (y1 - y0) * (x - x0) / safe;

            float r;
            if (x <= cdft[0])              r = csv(0);
            else if (x >= cdft[NBINS - 1]) r = csv(NBINS - 1);
            else                           r = interp;

            pxmap[c * NBINS + t] = r;
        }
    }

    __threadfence();
    grid.sync();

    // ---------------- Phase C: map ----------------
    for (int i = t; i < 3 * NBINS; i += FTH) pm[i] = pxmap[i];
    for (int i = t; i < NBINS; i += FTH) cstab[i] = csv(i);
    __syncthreads();

    float4* __restrict__ o4 = (float4*)out;
    for (int g = blockIdx.x * blockDim.x + t; g < ngroups; g += stride) {
        int b = g * 3;
        float4 s0 = s4[b], s1 = s4[b + 1], s2 = s4[b + 2];
        float4 r0, r1, r2;
        r0.x = map_one(s0.x, &pm[0 * NBINS], cstab);
        r0.y = map_one(s0.y, &pm[1 * NBINS], cstab);
        r0.z = map_one(s0.z, &pm[2 * NBINS], cstab);
        r0.w = map_one(s0.w, &pm[0 * NBINS], cstab);
        r1.x = map_one(s1.x, &pm[1 * NBINS], cstab);
        r1.y = map_one(s1.y, &pm[2 * NBINS], cstab);
        r1.z = map_one(s1.z, &pm[0 * NBINS], cstab);
        r1.w = map_one(s1.w, &pm[1 * NBINS], cstab);
        r2.x = map_one(s2.x, &pm[2 * NBINS], cstab);
        r2.y = map_one(s2.y, &pm[0 * NBINS], cstab);
        r2.z = map_one(s2.z, &pm[1 * NBINS], cstab);
        r2.w = map_one(s2.w, &pm[2 * NBINS], cstab);
        o4[b] = r0; o4[b + 1] = r1; o4[b + 2] = r2;
    }
    if (blockIdx.x == 0) {
        int base = ngroups * 12;
        int rem = n - base;
        if (t < rem) {
            int j = base + t;
            int c = j % 3;
            out[j] = map_one(src[j], &pm[c * NBINS], cstab);
        }
    }
}

// ===========================================================================
// Fallback path: the verified round-0 4-kernel structure (93.5 us), used only
// if the cooperative launch is rejected (e.g. by graph capture) or ws is tiny.
// ===========================================================================
__global__ __launch_bounds__(256) void hm_hist(const float* __restrict__ src,
                                               const float* __restrict__ tgt,
                                               int ngroups, int n,
                                               int* __restrict__ partials) {
    __shared__ int lh[SLOT];
    for (int i = threadIdx.x; i < SLOT; i += blockDim.x) lh[i] = 0;
    __syncthreads();

    const float4* __restrict__ s4 = (const float4*)src;
    const float4* __restrict__ t4 = (const float4*)tgt;
    const int stride = gridDim.x * blockDim.x;
    for (int g = blockIdx.x * blockDim.x + threadIdx.x; g < ngroups; g += stride) {
        int b = g * 3;
        float4 s0 = s4[b], s1 = s4[b + 1], s2 = s4[b + 2];
        float4 t0 = t4[b], t1 = t4[b + 1], t2 = t4[b + 2];
        atomicAdd(&lh[0 * NBINS + binof(s0.x)], 1);
        atomicAdd(&lh[1 * NBINS + binof(s0.y)], 1);
        atomicAdd(&lh[2 * NBINS + binof(s0.z)], 1);
        atomicAdd(&lh[0 * NBINS + binof(s0.w)], 1);
        atomicAdd(&lh[1 * NBINS + binof(s1.x)], 1);
        atomicAdd(&lh[2 * NBINS + binof(s1.y)], 1);
        atomicAdd(&lh[0 * NBINS + binof(s1.z)], 1);
        atomicAdd(&lh[1 * NBINS + binof(s1.w)], 1);
        atomicAdd(&lh[2 * NBINS + binof(s2.x)], 1);
        atomicAdd(&lh[0 * NBINS + binof(s2.y)], 1);
        atomicAdd(&lh[1 * NBINS + binof(s2.z)], 1);
        atomicAdd(&lh[2 * NBINS + binof(s2.w)], 1);
        atomicAdd(&lh[3 * NBINS + binof(t0.x)], 1);
        atomicAdd(&lh[4 * NBINS + binof(t0.y)], 1);
        atomicAdd(&lh[5 * NBINS + binof(t0.z)], 1);
        atomicAdd(&lh[3 * NBINS + binof(t0.w)], 1);
        atomicAdd(&lh[4 * NBINS + binof(t1.x)], 1);
        atomicAdd(&lh[5 * NBINS + binof(t1.y)], 1);
        atomicAdd(&lh[3 * NBINS + binof(t1.z)], 1);
        atomicAdd(&lh[4 * NBINS + binof(t1.w)], 1);
        atomicAdd(&lh[5 * NBINS + binof(t2.x)], 1);
        atomicAdd(&lh[3 * NBINS + binof(t2.y)], 1);
        atomicAdd(&lh[4 * NBINS + binof(t2.z)], 1);
        atomicAdd(&lh[5 * NBINS + binof(t2.w)], 1);
    }
    if (blockIdx.x == 0) {
        int base = ngroups * 12;
        int rem = n - base;
        if ((int)threadIdx.x < rem) {
            int j = base + threadIdx.x;
            int c = j % 3;
            atomicAdd(&lh[c * NBINS + binof(src[j])], 1);
            atomicAdd(&lh[(3 + c) * NBINS + binof(tgt[j])], 1);
        }
    }
    __syncthreads();

    int* dst = partials + blockIdx.x * SLOT;
    for (int i = threadIdx.x; i < SLOT; i += blockDim.x) dst[i] = lh[i];
}

__global__ void hm_reduce(int* __restrict__ partials) {
    int h = blockIdx.x >> 4;
    int k = blockIdx.x & 15;
    int t = threadIdx.x;
    int base = (k * 16) * SLOT + h * NBINS + t;
    int s = 0;
    #pragma unroll
    for (int j = 0; j < 16; j++) s += partials[base + j * SLOT];
    partials[base] = s;
}

__global__ __launch_bounds__(1024) void hm_tables(const int* __restrict__ partials,
                                                  int nslots, int step,
                                                  float pixcnt_m1,
                                                  float* __restrict__ pxmap) {
    const int c = blockIdx.x;
    const int t = threadIdx.x;
    const int grp = t >> 8;
    const int bin = t & 255;

    __shared__ int red[8][NBINS];
    __shared__ int ss[NBINS], st[NBINS];
    __shared__ float cdfs[NBINS], cdft[NBINS];

    int as = 0, at = 0;
    for (int b = grp; b < nslots; b += 4) {
        const int* p = partials + (b * step) * SLOT;
        as += p[c * NBINS + bin];
        at += p[(3 + c) * NBINS + bin];
    }
    red[grp][bin] = as;
    red[4 + grp][bin] = at;
    __syncthreads();

    if (t < NBINS) {
        ss[t] = red[0][t] + red[1][t] + red[2][t] + red[3][t];
        st[t] = red[4][t] + red[5][t] + red[6][t] + red[7][t];
    }
    __syncthreads();

    for (int off = 1; off < NBINS; off <<= 1) {
        int a = 0, b = 0;
        if (t < NBINS && t >= off) { a = ss[t - off]; b = st[t - off]; }
        __syncthreads();
        if (t < NBINS && t >= off) { ss[t] += a; st[t] += b; }
        __syncthreads();
    }

    if (t < NBINS) {
        int mins = ss[0];
        int mint = st[0];
        cdfs[t] = (float)(ss[t] - mins) * 2.0f / pixcnt_m1 - 1.0f;
        cdft[t] = (float)(st[t] - mint) * 2.0f / pixcnt_m1 - 1.0f;
    }
    __syncthreads();

    if (t < NBINS) {
        float x = cdfs[t];
        int ind1 = 0;
        float best = fabsf(cdft[0] - x);
        for (int i = 1; i < NBINS; i++) {
            float d = fabsf(cdft[i] - x);
            if (d < best) { best = d; ind1 = i; }
        }
        int ind0 = max(ind1 - 1, 0);
        float x0 = cdft[ind0], x1 = cdft[ind1];
        float y0 = csv(ind0),  y1 = csv(ind1);
        float denom = x1 - x0;
        float safe = (denom == 0.0f) ? 1.0f : denom;
        float interp = y0 + (y1 - y0) * (x - x0) / safe;

        float r;
        if (x <= cdft[0])              r = csv(0);
        else if (x >= cdft[NBINS - 1]) r = csv(NBINS - 1);
        else                           r = interp;

        pxmap[c * NBINS + t] = r;
    }
}

__global__ __launch_bounds__(256) void hm_map(const float* __restrict__ src,
                                              const float* __restrict__ pxmap,
                                              float* __restrict__ out,
                                              int ngroups, int n) {
    __shared__ float pm[3 * NBINS];
    __shared__ float cs[NBINS];
    for (int i = threadIdx.x; i < 3 * NBINS; i += blockDim.x) pm[i] = pxmap[i];
    for (int i = threadIdx.x; i < NBINS; i += blockDim.x) cs[i] = csv(i);
    __syncthreads();

    const float4* __restrict__ s4 = (const float4*)src;
    float4* __restrict__ o4 = (float4*)out;
    const int stride = gridDim.x * blockDim.x;
    for (int g = blockIdx.x * blockDim.x + threadIdx.x; g < ngroups; g += stride) {
        int b = g * 3;
        float4 s0 = s4[b], s1 = s4[b + 1], s2 = s4[b + 2];
        float4 r0, r1, r2;
        r0.x = map_one(s0.x, &pm[0 * NBINS], cs);
        r0.y = map_one(s0.y, &pm[1 * NBINS], cs);
        r0.z = map_one(s0.z, &pm[2 * NBINS], cs);
        r0.w = map_one(s0.w, &pm[0 * NBINS], cs);
        r1.x = map_one(s1.x, &pm[1 * NBINS], cs);
        r1.y = map_one(s1.y, &pm[2 * NBINS], cs);
        r1.z = map_one(s1.z, &pm[0 * NBINS], cs);
        r1.w = map_one(s1.w, &pm[1 * NBINS], cs);
        r2.x = map_one(s2.x, &pm[2 * NBINS], cs);
        r2.y = map_one(s2.y, &pm[0 * NBINS], cs);
        r2.z = map_one(s2.z, &pm[1 * NBINS], cs);
        r2.w = map_one(s2.w, &pm[2 * NBINS], cs);
        o4[b] = r0; o4[b + 1] = r1; o4[b + 2] = r2;
    }
    if (blockIdx.x == 0) {
        int base = ngroups * 12;
        int rem = n - base;
        if ((int)threadIdx.x < rem) {
            int j = base + threadIdx.x;
            int c = j % 3;
            out[j] = map_one(src[j], &pm[c * NBINS], cs);
        }
    }
}

extern "C" void kernel_launch(void* const* d_in, const int* in_sizes, int n_in,
                              void* d_out, int out_size, void* d_ws, size_t ws_size,
                              hipStream_t stream) {
    const float* src = (const float*)d_in[0];
    const float* tgt = (const float*)d_in[1];
    float* out = (float*)d_out;

    const int n = in_sizes[0];       // H*W*3
    const int ngroups = n / 12;      // 12-element (3x float4) groups
    const int pixcnt = n / 3;        // H*W

    // ws layout: [0, 4096): pxmap (3*256 floats); [4096, ...): partials
    float* pxmap    = (float*)d_ws;
    int*   partials = (int*)((char*)d_ws + 4096);

    const int slot_bytes = SLOT * (int)sizeof(int);   // 6 KiB per slot
    float pixm1 = (float)pixcnt - 1.0f;

    // Cooperative fused path: 256 blocks x 1024 threads (1 block/CU).
    bool coop_ok = (ws_size >= 4096 + (size_t)FNB * slot_bytes) && (ngroups >= 1);
    if (coop_ok) {
        const float* a_src = src; const float* a_tgt = tgt; float* a_out = out;
        int a_ng = ngroups; int a_n = n; float a_px = pixm1;
        float* a_pm = pxmap; int* a_pt = partials;
        void* kargs[] = {(void*)&a_src, (void*)&a_tgt, (void*)&a_out,
                         (void*)&a_ng, (void*)&a_n, (void*)&a_px,
                         (void*)&a_pm, (void*)&a_pt};
        hipError_t e = hipLaunchCooperativeKernel((const void*)hm_fused,
                                                  dim3(FNB), dim3(FTH),
                                                  kargs, 0, stream);
        if (e == hipSuccess) return;
        (void)hipGetLastError();   // clear, fall through to fallback
    }

    // ---- fallback: verified round-0 structure ----
    int NB = 256;
    int need = (ngroups + 255) / 256;
    if (need < 1) need = 1;
    if (NB > need) NB = need;
    if (ws_size >= 4096 + (size_t)slot_bytes) {
        size_t avail = (ws_size - 4096) / slot_bytes;
        if (avail < (size_t)NB) NB = (int)avail;
    } else {
        NB = 1;
    }

    hm_hist<<<NB, 256, 0, stream>>>(src, tgt, ngroups, n, partials);

    if (NB == 256) {
        hm_reduce<<<96, NBINS, 0, stream>>>(partials);
        hm_tables<<<3, 1024, 0, stream>>>(partials, 16, 16, pixm1, pxmap);
    } else {
        hm_tables<<<3, 1024, 0, stream>>>(partials, NB, 1, pixm1, pxmap);
    }

    int mblocks = (ngroups + 255) / 256;
    if (mblocks > 1024) mblocks = 1024;
    if (mblocks < 1) mblocks = 1;
    hm_map<<<mblocks, 256, 0, stream>>>(src, pxmap, out, ngroups, n);
}

// Round 5
// 122.255 us; speedup vs baseline: 2.4129x; 2.4129x over previous
//
#include <hip/hip_runtime.h>

#define NBINS 256
#define SLOT (6 * NBINS)   // ints per histogram set (6 channels x 256 bins)
#define NCOPY 4            // contention-splitting copies of the global hist

// cs[i] = clip(-1 + i/127, -1, 1) computed exactly as the reference (fp32 ops)
__device__ __forceinline__ float csv(int i) {
    float c = -1.0f + (float)i / 127.0f;
    return fminf(fmaxf(c, -1.0f), 1.0f);
}

__device__ __forceinline__ int binof(float v) {
    v = fminf(fmaxf(v, -1.0f), 1.0f);
    int b = (int)((v + 1.0f) * 128.0f);   // trunc toward zero == astype(int32)
    return min(max(b, 0), NBINS - 1);
}

__device__ __forceinline__ float map_one(float x, const float* __restrict__ y,
                                         const float* __restrict__ cs) {
    if (x <= -1.0f) return y[0];
    if (x >= 1.0f)  return y[NBINS - 1];
    float kf = (x + 1.0f) * 127.0f;
    int k = (int)(kf + 0.5f);
    int lo = max(k - 1, 0);
    int hi = min(k + 1, NBINS - 1);
    int ind1 = lo;
    float best = fabsf(cs[lo] - x);
    for (int j = lo + 1; j <= hi; j++) {
        float d = fabsf(cs[j] - x);
        if (d < best) { best = d; ind1 = j; }   // strict < => first-min
    }
    int ind0 = max(ind1 - 1, 0);
    float x0 = cs[ind0], x1 = cs[ind1];
    float y0 = y[ind0],  y1 = y[ind1];
    float denom = x1 - x0;
    float safe = (denom == 0.0f) ? 1.0f : denom;
    return y0 + (y1 - y0) * (x - x0) / safe;
}

// ---------------------------------------------------------------------------
// Kernel 1: per-block private LDS histograms -> device-scope atomicAdd into
// ghist[NCOPY][6][256] (4 copies cut per-cacheline contention 4x). Then the
// LAST block to finish (done-counter) computes scan + pxmap inline.
// No grid-wide sync anywhere (round-4 lesson: grid.sync ~100us on 8 XCDs).
// ---------------------------------------------------------------------------
__global__ __launch_bounds__(256) void hm_hist_tables(const float* __restrict__ src,
                                                      const float* __restrict__ tgt,
                                                      int ngroups, int n,
                                                      float pixcnt_m1,
                                                      int* __restrict__ ghist,
                                                      unsigned int* __restrict__ done,
                                                      float* __restrict__ pxmap) {
    __shared__ int lh[SLOT];
    const int t = threadIdx.x;
    for (int i = t; i < SLOT; i += blockDim.x) lh[i] = 0;
    __syncthreads();

    const float4* __restrict__ s4 = (const float4*)src;
    const float4* __restrict__ t4 = (const float4*)tgt;
    const int stride = gridDim.x * blockDim.x;
    for (int g = blockIdx.x * blockDim.x + t; g < ngroups; g += stride) {
        int b = g * 3;   // float4 index; covers flat elements 12g .. 12g+11
        float4 s0 = s4[b], s1 = s4[b + 1], s2 = s4[b + 2];
        float4 t0 = t4[b], t1 = t4[b + 1], t2 = t4[b + 2];
        // channels of elements 12g+0..11 are 0,1,2 repeating
        atomicAdd(&lh[0 * NBINS + binof(s0.x)], 1);
        atomicAdd(&lh[1 * NBINS + binof(s0.y)], 1);
        atomicAdd(&lh[2 * NBINS + binof(s0.z)], 1);
        atomicAdd(&lh[0 * NBINS + binof(s0.w)], 1);
        atomicAdd(&lh[1 * NBINS + binof(s1.x)], 1);
        atomicAdd(&lh[2 * NBINS + binof(s1.y)], 1);
        atomicAdd(&lh[0 * NBINS + binof(s1.z)], 1);
        atomicAdd(&lh[1 * NBINS + binof(s1.w)], 1);
        atomicAdd(&lh[2 * NBINS + binof(s2.x)], 1);
        atomicAdd(&lh[0 * NBINS + binof(s2.y)], 1);
        atomicAdd(&lh[1 * NBINS + binof(s2.z)], 1);
        atomicAdd(&lh[2 * NBINS + binof(s2.w)], 1);

        atomicAdd(&lh[3 * NBINS + binof(t0.x)], 1);
        atomicAdd(&lh[4 * NBINS + binof(t0.y)], 1);
        atomicAdd(&lh[5 * NBINS + binof(t0.z)], 1);
        atomicAdd(&lh[3 * NBINS + binof(t0.w)], 1);
        atomicAdd(&lh[4 * NBINS + binof(t1.x)], 1);
        atomicAdd(&lh[5 * NBINS + binof(t1.y)], 1);
        atomicAdd(&lh[3 * NBINS + binof(t1.z)], 1);
        atomicAdd(&lh[4 * NBINS + binof(t1.w)], 1);
        atomicAdd(&lh[5 * NBINS + binof(t2.x)], 1);
        atomicAdd(&lh[3 * NBINS + binof(t2.y)], 1);
        atomicAdd(&lh[4 * NBINS + binof(t2.z)], 1);
        atomicAdd(&lh[5 * NBINS + binof(t2.w)], 1);
    }
    // scalar tail (n not divisible by 12)
    if (blockIdx.x == 0) {
        int base = ngroups * 12;
        int rem = n - base;
        if (t < rem) {
            int j = base + t;
            int c = j % 3;
            atomicAdd(&lh[c * NBINS + binof(src[j])], 1);
            atomicAdd(&lh[(3 + c) * NBINS + binof(tgt[j])], 1);
        }
    }
    __syncthreads();

    // Flush LDS hist -> one of NCOPY global copies (device-scope atomics).
    {
        int* gdst = ghist + (blockIdx.x & (NCOPY - 1)) * SLOT;
        for (int i = t; i < SLOT; i += blockDim.x) {
            int v = lh[i];
            if (v) atomicAdd(&gdst[i], v);
        }
    }

    // ---- last-block-done: only the final block proceeds (no waiting) ----
    __shared__ unsigned int is_last;
    __threadfence();                       // make our atomics globally visible
    __syncthreads();
    if (t == 0) {
        unsigned int prev = atomicAdd(done, 1u);
        is_last = (prev == gridDim.x - 1) ? 1u : 0u;
    }
    __syncthreads();
    if (!is_last) return;
    __threadfence();                       // acquire side

    // ---- tables: 256 threads, 3 channels sequentially ----
    __shared__ int ss[NBINS], st[NBINS];
    __shared__ float cdfs[NBINS], cdft[NBINS];

    for (int c = 0; c < 3; ++c) {
        int a0 = 0, a1 = 0;
        #pragma unroll
        for (int k = 0; k < NCOPY; ++k) {
            a0 += __hip_atomic_load(&ghist[k * SLOT + c * NBINS + t],
                                    __ATOMIC_RELAXED, __HIP_MEMORY_SCOPE_AGENT);
            a1 += __hip_atomic_load(&ghist[k * SLOT + (3 + c) * NBINS + t],
                                    __ATOMIC_RELAXED, __HIP_MEMORY_SCOPE_AGENT);
        }
        ss[t] = a0;
        st[t] = a1;
        __syncthreads();

        // Hillis-Steele inclusive scan of both arrays (integer => exact)
        for (int off = 1; off < NBINS; off <<= 1) {
            int a = 0, b = 0;
            if (t >= off) { a = ss[t - off]; b = st[t - off]; }
            __syncthreads();
            if (t >= off) { ss[t] += a; st[t] += b; }
            __syncthreads();
        }

        // cdf nondecreasing -> min = cdf[0]; exact ref op order
        cdfs[t] = (float)(ss[t] - ss[0]) * 2.0f / pixcnt_m1 - 1.0f;
        cdft[t] = (float)(st[t] - st[0]) * 2.0f / pixcnt_m1 - 1.0f;
        __syncthreads();

        // pxmap[t] = _interpolate(dx=cdftgt, dy=cs, x=cdfsrc[t]); first-min argmin
        {
            float x = cdfs[t];
            int ind1 = 0;
            float best = fabsf(cdft[0] - x);
            for (int i = 1; i < NBINS; i++) {
                float d = fabsf(cdft[i] - x);
                if (d < best) { best = d; ind1 = i; }
            }
            int ind0 = max(ind1 - 1, 0);
            float x0 = cdft[ind0], x1 = cdft[ind1];
            float y0 = csv(ind0),  y1 = csv(ind1);
            float denom = x1 - x0;
            float safe = (denom == 0.0f) ? 1.0f : denom;
            float interp = y0 + (y1 - y0) * (x - x0) / safe;

            float r;
            if (x <= cdft[0])              r = csv(0);
            else if (x >= cdft[NBINS - 1]) r = csv(NBINS - 1);
            else                           r = interp;

            pxmap[c * NBINS + t] = r;
        }
        __syncthreads();   // ss/st/cdfs/cdft reused next channel
    }
}

// ---------------------------------------------------------------------------
// Kernel 2: mapped = _interpolate(dx=cs, dy=pxmap[c], x=src). 12-elem groups,
// compile-time channels, cs table in LDS (no fp32 divides for grid values).
// (verified round-0 kernel, unchanged)
// ---------------------------------------------------------------------------
__global__ __launch_bounds__(256) void hm_map(const float* __restrict__ src,
                                              const float* __restrict__ pxmap,
                                              float* __restrict__ out,
                                              int ngroups, int n) {
    __shared__ float pm[3 * NBINS];
    __shared__ float cs[NBINS];
    for (int i = threadIdx.x; i < 3 * NBINS; i += blockDim.x) pm[i] = pxmap[i];
    for (int i = threadIdx.x; i < NBINS; i += blockDim.x) cs[i] = csv(i);
    __syncthreads();

    const float4* __restrict__ s4 = (const float4*)src;
    float4* __restrict__ o4 = (float4*)out;
    const int stride = gridDim.x * blockDim.x;
    for (int g = blockIdx.x * blockDim.x + threadIdx.x; g < ngroups; g += stride) {
        int b = g * 3;
        float4 s0 = s4[b], s1 = s4[b + 1], s2 = s4[b + 2];
        float4 r0, r1, r2;
        r0.x = map_one(s0.x, &pm[0 * NBINS], cs);
        r0.y = map_one(s0.y, &pm[1 * NBINS], cs);
        r0.z = map_one(s0.z, &pm[2 * NBINS], cs);
        r0.w = map_one(s0.w, &pm[0 * NBINS], cs);
        r1.x = map_one(s1.x, &pm[1 * NBINS], cs);
        r1.y = map_one(s1.y, &pm[2 * NBINS], cs);
        r1.z = map_one(s1.z, &pm[0 * NBINS], cs);
        r1.w = map_one(s1.w, &pm[1 * NBINS], cs);
        r2.x = map_one(s2.x, &pm[2 * NBINS], cs);
        r2.y = map_one(s2.y, &pm[0 * NBINS], cs);
        r2.z = map_one(s2.z, &pm[1 * NBINS], cs);
        r2.w = map_one(s2.w, &pm[2 * NBINS], cs);
        o4[b] = r0; o4[b + 1] = r1; o4[b + 2] = r2;
    }
    // scalar tail
    if (blockIdx.x == 0) {
        int base = ngroups * 12;
        int rem = n - base;
        if ((int)threadIdx.x < rem) {
            int j = base + threadIdx.x;
            int c = j % 3;
            out[j] = map_one(src[j], &pm[c * NBINS], cs);
        }
    }
}

extern "C" void kernel_launch(void* const* d_in, const int* in_sizes, int n_in,
                              void* d_out, int out_size, void* d_ws, size_t ws_size,
                              hipStream_t stream) {
    const float* src = (const float*)d_in[0];
    const float* tgt = (const float*)d_in[1];
    float* out = (float*)d_out;

    const int n = in_sizes[0];       // H*W*3
    const int ngroups = n / 12;      // 12-element (3x float4) groups
    const int pixcnt = n / 3;        // H*W
    float pixm1 = (float)pixcnt - 1.0f;

    // ws layout:
    //   [0, 4096):             pxmap (3*256 floats)
    //   [4096, 4096+24576):    ghist (NCOPY * 6 * 256 ints)
    //   [4096+24576, +4):      done counter
    float*        pxmap = (float*)d_ws;
    int*          ghist = (int*)((char*)d_ws + 4096);
    unsigned int* done  = (unsigned int*)((char*)d_ws + 4096 + NCOPY * SLOT * sizeof(int));

    // zero ghist + done (workspace is poisoned each iteration)
    hipMemsetAsync((char*)d_ws + 4096, 0,
                   NCOPY * SLOT * sizeof(int) + sizeof(unsigned int), stream);

    int NB = 256;                    // 1 block/CU; each block fully saturates its
                                     // HBM share (24KB in flight > 9KB BW*lat)
    int need = (ngroups + 255) / 256;
    if (need < 1) need = 1;
    if (NB > need) NB = need;

    hm_hist_tables<<<NB, 256, 0, stream>>>(src, tgt, ngroups, n, pixm1,
                                           ghist, done, pxmap);

    int mblocks = (ngroups + 255) / 256;
    if (mblocks > 1024) mblocks = 1024;
    if (mblocks < 1) mblocks = 1;
    hm_map<<<mblocks, 256, 0, stream>>>(src, pxmap, out, ngroups, n);
}

// Round 7
// 94.471 us; speedup vs baseline: 3.1226x; 1.2941x over previous
//
#include <hip/hip_runtime.h>

#define NBINS 256
#define SLOT (6 * NBINS)   // ints per partial-histogram slot
#define HTH 1024           // hist block size (16 waves/CU)
#define NSUB 4             // LDS sub-histograms per hist block

// cs[i] = clip(-1 + i/127, -1, 1) computed exactly as the reference (fp32 ops)
__device__ __forceinline__ float csv(int i) {
    float c = -1.0f + (float)i / 127.0f;
    return fminf(fmaxf(c, -1.0f), 1.0f);
}

__device__ __forceinline__ int binof(float v) {
    v = fminf(fmaxf(v, -1.0f), 1.0f);
    int b = (int)((v + 1.0f) * 128.0f);   // trunc toward zero == astype(int32)
    return min(max(b, 0), NBINS - 1);
}

// ---------------------------------------------------------------------------
// Kernel 1: per-block private histograms -> partials[blockIdx][6][256]
// (non-atomic flush; r5 lesson: device-scope atomic flush costs ~+25us).
// 1024 threads/block (16 waves/CU) for memory-level parallelism on the 25MB
// read; 4 LDS sub-histograms (one per 4-wave cluster) cut LDS-atomic
// contention 4x. Each thread handles one group of 12 consecutive elements
// (= 3 float4 loads) so channel indices are compile-time constants.
// Grid must be exactly NB blocks (each owns one partials slot).
// ---------------------------------------------------------------------------
__global__ __launch_bounds__(HTH) void hm_hist(const float* __restrict__ src,
                                               const float* __restrict__ tgt,
                                               int ngroups, int n,
                                               int* __restrict__ partials) {
    __shared__ int lh[NSUB][SLOT];        // 24 KiB
    const int t = threadIdx.x;
    {
        int* l0 = &lh[0][0];
        for (int i = t; i < NSUB * SLOT; i += HTH) l0[i] = 0;
    }
    __syncthreads();

    int* __restrict__ mylh = lh[(t >> 6) & (NSUB - 1)];   // wave w -> sub w&3

    const float4* __restrict__ s4 = (const float4*)src;
    const float4* __restrict__ t4 = (const float4*)tgt;
    const int stride = gridDim.x * blockDim.x;
    for (int g = blockIdx.x * blockDim.x + t; g < ngroups; g += stride) {
        int b = g * 3;   // float4 index; covers flat elements 12g .. 12g+11
        float4 s0 = s4[b], s1 = s4[b + 1], s2 = s4[b + 2];
        float4 t0 = t4[b], t1 = t4[b + 1], t2 = t4[b + 2];
        // channels of elements 12g+0..11 are 0,1,2 repeating
        atomicAdd(&mylh[0 * NBINS + binof(s0.x)], 1);
        atomicAdd(&mylh[1 * NBINS + binof(s0.y)], 1);
        atomicAdd(&mylh[2 * NBINS + binof(s0.z)], 1);
        atomicAdd(&mylh[0 * NBINS + binof(s0.w)], 1);
        atomicAdd(&mylh[1 * NBINS + binof(s1.x)], 1);
        atomicAdd(&mylh[2 * NBINS + binof(s1.y)], 1);
        atomicAdd(&mylh[0 * NBINS + binof(s1.z)], 1);
        atomicAdd(&mylh[1 * NBINS + binof(s1.w)], 1);
        atomicAdd(&mylh[2 * NBINS + binof(s2.x)], 1);
        atomicAdd(&mylh[0 * NBINS + binof(s2.y)], 1);
        atomicAdd(&mylh[1 * NBINS + binof(s2.z)], 1);
        atomicAdd(&mylh[2 * NBINS + binof(s2.w)], 1);

        atomicAdd(&mylh[3 * NBINS + binof(t0.x)], 1);
        atomicAdd(&mylh[4 * NBINS + binof(t0.y)], 1);
        atomicAdd(&mylh[5 * NBINS + binof(t0.z)], 1);
        atomicAdd(&mylh[3 * NBINS + binof(t0.w)], 1);
        atomicAdd(&mylh[4 * NBINS + binof(t1.x)], 1);
        atomicAdd(&mylh[5 * NBINS + binof(t1.y)], 1);
        atomicAdd(&mylh[3 * NBINS + binof(t1.z)], 1);
        atomicAdd(&mylh[4 * NBINS + binof(t1.w)], 1);
        atomicAdd(&mylh[5 * NBINS + binof(t2.x)], 1);
        atomicAdd(&mylh[3 * NBINS + binof(t2.y)], 1);
        atomicAdd(&mylh[4 * NBINS + binof(t2.z)], 1);
        atomicAdd(&mylh[5 * NBINS + binof(t2.w)], 1);
    }
    // scalar tail (n not divisible by 12); t<12 lies in wave 0 -> sub 0
    if (blockIdx.x == 0) {
        int base = ngroups * 12;
        int rem = n - base;
        if (t < rem) {
            int j = base + t;
            int c = j % 3;
            atomicAdd(&mylh[c * NBINS + binof(src[j])], 1);
            atomicAdd(&mylh[(3 + c) * NBINS + binof(tgt[j])], 1);
        }
    }
    __syncthreads();

    // non-atomic merged flush
    int* dst = partials + blockIdx.x * SLOT;
    for (int i = t; i < SLOT; i += HTH)
        dst[i] = lh[0][i] + lh[1][i] + lh[2][i] + lh[3][i];
}

// ---------------------------------------------------------------------------
// Kernel 1.5: parallel level-1 reduction of 256 partial slots -> 16 slots
// (result for group k lands in slot 16*k). Block b: h = b/16 (histogram 0..5),
// k = b%16 (group). Each thread sums 16 independent loads (fully pipelined).
// (verified round-0 kernel, unchanged)
// ---------------------------------------------------------------------------
__global__ void hm_reduce(int* __restrict__ partials) {
    int h = blockIdx.x >> 4;    // 0..5
    int k = blockIdx.x & 15;    // 0..15
    int t = threadIdx.x;
    int base = (k * 16) * SLOT + h * NBINS + t;
    int s = 0;
    #pragma unroll
    for (int j = 0; j < 16; j++) s += partials[base + j * SLOT];
    partials[base] = s;
}

// ---------------------------------------------------------------------------
// Kernel 2: 3 blocks (one per channel) x 1024 threads. 4 thread-groups of 256
// reduce nslots slots (spaced `step` apart) in parallel, LDS-combine, then
// scan -> cdfs/cdft -> pxmap = _interpolate(cdftgt, cs, cdfsrc).
// (verified round-0 kernel, unchanged)
// ---------------------------------------------------------------------------
__global__ __launch_bounds__(1024) void hm_tables(const int* __restrict__ partials,
                                                  int nslots, int step,
                                                  float pixcnt_m1,
                                                  float* __restrict__ pxmap) {
    const int c = blockIdx.x;
    const int t = threadIdx.x;
    const int grp = t >> 8;     // 0..3
    const int bin = t & 255;

    __shared__ int red[8][NBINS];          // [grp] src, [4+grp] tgt
    __shared__ int ss[NBINS], st[NBINS];
    __shared__ float cdfs[NBINS], cdft[NBINS];

    int as = 0, at = 0;
    for (int b = grp; b < nslots; b += 4) {
        const int* p = partials + (b * step) * SLOT;
        as += p[c * NBINS + bin];
        at += p[(3 + c) * NBINS + bin];
    }
    red[grp][bin] = as;
    red[4 + grp][bin] = at;
    __syncthreads();

    if (t < NBINS) {
        ss[t] = red[0][t] + red[1][t] + red[2][t] + red[3][t];
        st[t] = red[4][t] + red[5][t] + red[6][t] + red[7][t];
    }
    __syncthreads();

    // Hillis-Steele inclusive scan (256 active lanes; all threads hit barriers)
    for (int off = 1; off < NBINS; off <<= 1) {
        int a = 0, b = 0;
        if (t < NBINS && t >= off) { a = ss[t - off]; b = st[t - off]; }
        __syncthreads();
        if (t < NBINS && t >= off) { ss[t] += a; st[t] += b; }
        __syncthreads();
    }

    if (t < NBINS) {
        // cdf nondecreasing -> min = cdf[0]; exact ref op order
        int mins = ss[0];
        int mint = st[0];
        cdfs[t] = (float)(ss[t] - mins) * 2.0f / pixcnt_m1 - 1.0f;
        cdft[t] = (float)(st[t] - mint) * 2.0f / pixcnt_m1 - 1.0f;
    }
    __syncthreads();

    if (t < NBINS) {
        // pxmap[t] = _interpolate(dx=cdftgt, dy=cs, x=cdfsrc[t]); first-min argmin
        float x = cdfs[t];
        int ind1 = 0;
        float best = fabsf(cdft[0] - x);
        for (int i = 1; i < NBINS; i++) {
            float d = fabsf(cdft[i] - x);
            if (d < best) { best = d; ind1 = i; }
        }
        int ind0 = max(ind1 - 1, 0);
        float x0 = cdft[ind0], x1 = cdft[ind1];
        float y0 = csv(ind0),  y1 = csv(ind1);
        float denom = x1 - x0;
        float safe = (denom == 0.0f) ? 1.0f : denom;
        float interp = y0 + (y1 - y0) * (x - x0) / safe;

        float r;
        if (x <= cdft[0])              r = csv(0);
        else if (x >= cdft[NBINS - 1]) r = csv(NBINS - 1);
        else                           r = interp;

        pxmap[c * NBINS + t] = r;
    }
}

// ---------------------------------------------------------------------------
// Kernel 3: mapped = _interpolate(dx=cs, dy=pxmap[c], x=src). 12-elem groups,
// compile-time channels, cs table in LDS (no fp32 divides for grid values).
// (verified round-0 kernel, unchanged)
// ---------------------------------------------------------------------------
__device__ __forceinline__ float map_one(float x, const float* __restrict__ y,
                                         const float* __restrict__ cs) {
    if (x <= -1.0f) return y[0];
    if (x >= 1.0f)  return y[NBINS - 1];
    float kf = (x + 1.0f) * 127.0f;
    int k = (int)(kf + 0.5f);
    int lo = max(k - 1, 0);
    int hi = min(k + 1, NBINS - 1);
    int ind1 = lo;
    float best = fabsf(cs[lo] - x);
    for (int j = lo + 1; j <= hi; j++) {
        float d = fabsf(cs[j] - x);
        if (d < best) { best = d; ind1 = j; }   // strict < => first-min
    }
    int ind0 = max(ind1 - 1, 0);
    float x0 = cs[ind0], x1 = cs[ind1];
    float y0 = y[ind0],  y1 = y[ind1];
    float denom = x1 - x0;
    float safe = (denom == 0.0f) ? 1.0f : denom;
    return y0 + (y1 - y0) * (x - x0) / safe;
}

__global__ __launch_bounds__(256) void hm_map(const float* __restrict__ src,
                                              const float* __restrict__ pxmap,
                                              float* __restrict__ out,
                                              int ngroups, int n) {
    __shared__ float pm[3 * NBINS];
    __shared__ float cs[NBINS];
    for (int i = threadIdx.x; i < 3 * NBINS; i += blockDim.x) pm[i] = pxmap[i];
    for (int i = threadIdx.x; i < NBINS; i += blockDim.x) cs[i] = csv(i);
    __syncthreads();

    const float4* __restrict__ s4 = (const float4*)src;
    float4* __restrict__ o4 = (float4*)out;
    const int stride = gridDim.x * blockDim.x;
    for (int g = blockIdx.x * blockDim.x + threadIdx.x; g < ngroups; g += stride) {
        int b = g * 3;
        float4 s0 = s4[b], s1 = s4[b + 1], s2 = s4[b + 2];
        float4 r0, r1, r2;
        r0.x = map_one(s0.x, &pm[0 * NBINS], cs);
        r0.y = map_one(s0.y, &pm[1 * NBINS], cs);
        r0.z = map_one(s0.z, &pm[2 * NBINS], cs);
        r0.w = map_one(s0.w, &pm[0 * NBINS], cs);
        r1.x = map_one(s1.x, &pm[1 * NBINS], cs);
        r1.y = map_one(s1.y, &pm[2 * NBINS], cs);
        r1.z = map_one(s1.z, &pm[0 * NBINS], cs);
        r1.w = map_one(s1.w, &pm[1 * NBINS], cs);
        r2.x = map_one(s2.x, &pm[2 * NBINS], cs);
        r2.y = map_one(s2.y, &pm[0 * NBINS], cs);
        r2.z = map_one(s2.z, &pm[1 * NBINS], cs);
        r2.w = map_one(s2.w, &pm[2 * NBINS], cs);
        o4[b] = r0; o4[b + 1] = r1; o4[b + 2] = r2;
    }
    // scalar tail
    if (blockIdx.x == 0) {
        int base = ngroups * 12;
        int rem = n - base;
        if ((int)threadIdx.x < rem) {
            int j = base + threadIdx.x;
            int c = j % 3;
            out[j] = map_one(src[j], &pm[c * NBINS], cs);
        }
    }
}

extern "C" void kernel_launch(void* const* d_in, const int* in_sizes, int n_in,
                              void* d_out, int out_size, void* d_ws, size_t ws_size,
                              hipStream_t stream) {
    const float* src = (const float*)d_in[0];
    const float* tgt = (const float*)d_in[1];
    float* out = (float*)d_out;

    const int n = in_sizes[0];       // H*W*3
    const int ngroups = n / 12;      // 12-element (3x float4) groups
    const int pixcnt = n / 3;        // H*W

    // ws layout: [0, 4096): pxmap (3*256 floats); [4096, ...): partials
    float* pxmap    = (float*)d_ws;
    int*   partials = (int*)((char*)d_ws + 4096);

    const int slot_bytes = SLOT * (int)sizeof(int);   // 6 KiB per slot
    int NB = 256;                    // 256 slots: one hist block per CU
    int need = (ngroups + HTH - 1) / HTH;
    if (need < 1) need = 1;
    if (NB > need) NB = need;
    if (ws_size >= 4096 + (size_t)slot_bytes) {
        size_t avail = (ws_size - 4096) / slot_bytes;
        if (avail < (size_t)NB) NB = (int)avail;
    } else {
        NB = 1;
    }

    hm_hist<<<NB, HTH, 0, stream>>>(src, tgt, ngroups, n, partials);

    if (NB == 256) {
        // level-1 reduce: 256 slots -> 16 slots (indices 0,16,...,240)
        hm_reduce<<<96, NBINS, 0, stream>>>(partials);
        hm_tables<<<3, 1024, 0, stream>>>(partials, 16, 16,
                                          (float)pixcnt - 1.0f, pxmap);
    } else {
        hm_tables<<<3, 1024, 0, stream>>>(partials, NB, 1,
                                          (float)pixcnt - 1.0f, pxmap);
    }

    int mblocks = (ngroups + 255) / 256;
    if (mblocks > 1024) mblocks = 1024;
    if (mblocks < 1) mblocks = 1;
    hm_map<<<mblocks, 256, 0, stream>>>(src, pxmap, out, ngroups, n);
}